// Round 7
// baseline (327.421 us; speedup 1.0000x reference)
//
#include <hip/hip_runtime.h>
#include <hip/hip_bf16.h>

// ---- constants for this problem ----
#define BB 4
#define TT 2048
#define C_IN 1152
#define NE 1024
#define NH 16
#define HD 64
#define MM (BB*TT)          // 8192
#define N_QKV (3*NE)        // 3072

typedef __attribute__((ext_vector_type(8))) short s16x8;
typedef __attribute__((ext_vector_type(4))) float f32x4;

static __device__ __forceinline__ unsigned short f2bf(float x) {
    unsigned int u = __float_as_uint(x);
    unsigned int r = (u + 0x7fffu + ((u >> 16) & 1u)) >> 16;
    return (unsigned short)r;
}

// async global->LDS, 16 B per lane. LDS dest = wave-uniform base + lane*16.
static __device__ __forceinline__ void async16(const void* g, void* l) {
    __builtin_amdgcn_global_load_lds((const __attribute__((address_space(1))) void*)g,
                                     (__attribute__((address_space(3))) void*)l, 16, 0, 0);
}

// ---------------- LayerNorm: x fp32 [M][C_IN] -> h bf16 [M][C_IN] ----------------
__global__ __launch_bounds__(256) void ln_kernel(const float* __restrict__ x,
                                                 const float* __restrict__ w,
                                                 const float* __restrict__ b,
                                                 unsigned short* __restrict__ h) {
    const int row = blockIdx.x;
    const float* xr = x + (size_t)row * C_IN;
    float s = 0.f, sq = 0.f;
    for (int i = threadIdx.x; i < C_IN; i += 256) {
        float v = xr[i];
        s += v; sq += v * v;
    }
    for (int off = 1; off < 64; off <<= 1) {
        s  += __shfl_xor(s, off, 64);
        sq += __shfl_xor(sq, off, 64);
    }
    __shared__ float red[2][4];
    const int wid = threadIdx.x >> 6, lane = threadIdx.x & 63;
    if (lane == 0) { red[0][wid] = s; red[1][wid] = sq; }
    __syncthreads();
    s  = red[0][0] + red[0][1] + red[0][2] + red[0][3];
    sq = red[1][0] + red[1][1] + red[1][2] + red[1][3];
    const float mu  = s * (1.f / C_IN);
    const float var = sq * (1.f / C_IN) - mu * mu;
    const float rs  = rsqrtf(var + 1e-5f);
    unsigned short* hr = h + (size_t)row * C_IN;
    for (int i = threadIdx.x; i < C_IN; i += 256) {
        float v = (xr[i] - mu) * rs * w[i] + b[i];
        hr[i] = f2bf(v);
    }
}

// ------------- transpose+cast: in fp32 [K][N] -> out bf16 [N][K] -------------
__global__ __launch_bounds__(256) void transpose_cast(const float* __restrict__ in,
                                                      unsigned short* __restrict__ out,
                                                      int K, int N) {
    __shared__ float tile[32][33];
    const int n0 = blockIdx.x * 32, k0 = blockIdx.y * 32;
    const int tx = threadIdx.x & 31, ty = threadIdx.x >> 5;   // 32 x 8
    for (int i = ty; i < 32; i += 8)
        tile[i][tx] = in[(size_t)(k0 + i) * N + n0 + tx];
    __syncthreads();
    for (int i = ty; i < 32; i += 8)
        out[(size_t)(n0 + i) * K + k0 + tx] = f2bf(tile[tx][i]);
}

#define ATT_SC 0.18033688011112042f   /* (1/8) * log2(e) */

// ------------- GEMM: A bf16 [M][K] x Bt bf16 [N][K] + bias -> epilogue -------------
// Double-buffered global_load_lds staging, one barrier per k-tile.
// MODE 0: QKV with LDS-routed coalesced epilogue; t = batch-local (mg & 2047).
//         q is PRE-SCALED by ATT_SC (q only feeds scores; saves a v_mul per
//         score element in the attention hot loop).
// MODE 1: plain fp32 out [M][N] direct stores.
#define EP_STRIDE 136   /* ushort; 272 B rows keep 16 B alignment for b128 */
template <int MODE>
__global__ __launch_bounds__(256) void gemm_bt(const unsigned short* __restrict__ A,
                                               const unsigned short* __restrict__ Bt,
                                               const float* __restrict__ bias,
                                               void* __restrict__ outp,
                                               unsigned short* __restrict__ kb,
                                               unsigned short* __restrict__ vt,
                                               int M, int N, int K) {
    __shared__ unsigned short smem[16384];          // 32 KB
    unsigned short* As = smem;                      // [2][128*32]
    unsigned short* Bs = smem + 8192;
    const int tid = threadIdx.x;
    const int wid = tid >> 6, lane = tid & 63;
    const int wm = wid >> 1, wn = wid & 1;
    const int quad = lane >> 4, l16 = lane & 15;
    const int m0 = blockIdx.y * 128, n0 = blockIdx.x * 128;

    const int srow = wid * 32 + (lane >> 2);     // + {0,16}
    const int scol = (lane & 3) * 8;
    const unsigned short* gA = A  + (size_t)(m0 + srow) * K + scol;
    const unsigned short* gB = Bt + (size_t)(n0 + srow) * K + scol;
    const int lofs = (wid * 32) * 32;

    f32x4 acc[4][4] = {};

    async16(gA,          &As[lofs]);
    async16(gA + 16 * K, &As[lofs + 16 * 32]);
    async16(gB,          &Bs[lofs]);
    async16(gB + 16 * K, &Bs[lofs + 16 * 32]);

    const int nk = K >> 5;
    for (int kt = 0; kt < nk; kt++) {
        __syncthreads();
        const int cur = kt & 1;
        if (kt + 1 < nk) {
            const int kk = (kt + 1) << 5;
            const int nxt = (cur ^ 1) * 4096;
            async16(gA + kk,          &As[nxt + lofs]);
            async16(gA + kk + 16 * K, &As[nxt + lofs + 16 * 32]);
            async16(gB + kk,          &Bs[nxt + lofs]);
            async16(gB + kk + 16 * K, &Bs[nxt + lofs + 16 * 32]);
        }
        const int cb = cur * 4096;
        s16x8 af[4], bfb[4];
        for (int mi = 0; mi < 4; mi++)
            af[mi] = *(const s16x8*)&As[cb + (wm * 64 + mi * 16 + l16) * 32 + quad * 8];
        for (int ni = 0; ni < 4; ni++)
            bfb[ni] = *(const s16x8*)&Bs[cb + (wn * 64 + ni * 16 + l16) * 32 + quad * 8];
        for (int mi = 0; mi < 4; mi++)
            for (int ni = 0; ni < 4; ni++)
                acc[mi][ni] = __builtin_amdgcn_mfma_f32_16x16x32_bf16(af[mi], bfb[ni], acc[mi][ni], 0, 0, 0);
    }

    // bias into registers (+ ATT_SC pre-scale for the q third)
    const int which0 = n0 >> 10;
    const float sc = (MODE == 0 && which0 == 0) ? ATT_SC : 1.0f;
    for (int ni = 0; ni < 4; ni++) {
        const float bv = bias[n0 + wn * 64 + ni * 16 + l16];
        for (int mi = 0; mi < 4; mi++)
            for (int r = 0; r < 4; r++)
                acc[mi][ni][r] = (acc[mi][ni][r] + bv) * sc;
    }

    if (MODE == 1) {
        for (int mi = 0; mi < 4; mi++) {
            const int mbase = m0 + wm * 64 + mi * 16 + quad * 4;
            for (int ni = 0; ni < 4; ni++) {
                const int n_g = n0 + wn * 64 + ni * 16 + l16;
                for (int r = 0; r < 4; r++)
                    ((float*)outp)[(size_t)(mbase + r) * N + n_g] = acc[mi][ni][r];
            }
        }
        return;
    }

    // ---- MODE 0: LDS-routed coalesced epilogue ----
    const int which = n0 >> 10;                    // 0=q 1=k 2=v (uniform)
    const int bb = m0 >> 11;
    const int mloc = m0 & 2047;                    // batch-local time base
    unsigned short* T = smem;                      // [64][EP_STRIDE]

    if (which < 2) {
        // row layout [m_local 64][n_local 128]; two m-half passes
        unsigned short* qk = (which == 0) ? (unsigned short*)outp : kb;
        for (int pass = 0; pass < 2; pass++) {
            __syncthreads();
            if (wm == pass) {
                for (int mi = 0; mi < 4; mi++)
                    for (int ni = 0; ni < 4; ni++) {
                        const int nl = wn * 64 + ni * 16 + l16;
                        for (int r = 0; r < 4; r++)
                            T[(mi * 16 + quad * 4 + r) * EP_STRIDE + nl] = f2bf(acc[mi][ni][r]);
                    }
            }
            __syncthreads();
            const int ml = tid >> 2, c = tid & 3;
            const int t  = mloc + pass * 64 + ml;
            const int nl0 = c * 32;
            const int hh = ((n0 & 1023) >> 6) + (nl0 >> 6);
            const int d0 = nl0 & 63;
            unsigned short* dst = qk + ((size_t)(bb * 16 + hh) * TT + t) * HD + d0;
            const unsigned short* src = &T[ml * EP_STRIDE + nl0];
            for (int u = 0; u < 4; u++)
                *(s16x8*)(dst + u * 8) = *(const s16x8*)(src + u * 8);
        }
    } else {
        // transposed layout [n_local 64][m_local 128]; two n-half passes
        for (int pass = 0; pass < 2; pass++) {
            __syncthreads();
            if (wn == pass) {
                for (int mi = 0; mi < 4; mi++)
                    for (int ni = 0; ni < 4; ni++) {
                        const int nlh = ni * 16 + l16;
                        const int mlb = wm * 64 + mi * 16 + quad * 4;
                        for (int r = 0; r < 4; r += 2) {
                            const unsigned int pk = (unsigned int)f2bf(acc[mi][ni][r]) |
                                                    ((unsigned int)f2bf(acc[mi][ni][r + 1]) << 16);
                            *(unsigned int*)&T[nlh * EP_STRIDE + mlb + r] = pk;
                        }
                    }
            }
            __syncthreads();
            const int nlh = tid >> 2, c = tid & 3;
            const int hh = (n0 - 2048 + pass * 64) >> 6;
            unsigned short* dst = vt + ((size_t)(bb * 16 + hh) * HD + nlh) * TT + mloc + c * 32;
            const unsigned short* src = &T[nlh * EP_STRIDE + c * 32];
            for (int u = 0; u < 4; u++)
                *(s16x8*)(dst + u * 8) = *(const s16x8*)(src + u * 8);
        }
    }
}

// ------------- flash attention: S^T trick + ones-MFMA row sums -------------
// q (pre-scaled by ATT_SC), k [BH][T][64] bf16, vt [BH][64][T] bf16 -> y bf16 [B][T][NE]
// S^T = K*Q^T: lane's 4 C-values = 4 consecutive KEYS at fixed q=l16.
// Denominator: lacc = mfma(P_frag, ones) -> row sums in C-layout, r-index aligns
// with yacc's q-index (no cross-lane reduction needed at all).
#define PST 72                         /* shorts; 144 B rows, 16B-aligned */

__global__ __launch_bounds__(256) void attn_kernel(const unsigned short* __restrict__ qb,
                                                   const unsigned short* __restrict__ kb,
                                                   const unsigned short* __restrict__ vt,
                                                   unsigned short* __restrict__ yb) {
    __shared__ unsigned short Ks[2][64 * 64];
    __shared__ unsigned short Vs[2][64 * 64];
    __shared__ unsigned short Ps[4][2 * 16 * PST];   // per-wave, per-mf [16 q][PST]
    const int tid = threadIdx.x, wid = tid >> 6, lane = tid & 63;
    const int quad = lane >> 4, l16 = lane & 15;
    const int bh = blockIdx.x & 63;
    const int qblk = 15 - (blockIdx.x >> 6);         // longest-first (LPT packing)

    const unsigned short* qh = qb + (size_t)bh * TT * HD;
    const unsigned short* kh = kb + (size_t)bh * TT * HD;
    const unsigned short* vh = vt + (size_t)bh * HD * TT;
    unsigned short* ps = Ps[wid];

    const int q0w = qblk * 128 + wid * 32;           // this wave's 32 q-rows
    s16x8 aq[2][2];
    #pragma unroll
    for (int mf = 0; mf < 2; mf++) {
        aq[mf][0] = *(const s16x8*)&qh[(size_t)(q0w + mf * 16 + l16) * HD + quad * 8];
        aq[mf][1] = *(const s16x8*)&qh[(size_t)(q0w + mf * 16 + l16) * HD + 32 + quad * 8];
    }
    // ones B-frag (bf16 1.0 = 0x3F80)
    s16x8 onesf;
    #pragma unroll
    for (int i = 0; i < 8; i++) onesf[i] = (short)0x3F80;

    f32x4 yacc[2][4] = {};
    f32x4 lacc[2] = {};                              // row-sum accumulators
    const int ntiles = 2 * qblk + 2;

    // hoisted staging pointers: row r = wid*16 + grp*8 + rl, chunk c XOR-swizzled
    const int rl = lane >> 3;
    const int cc = (lane & 7) ^ (rl & 7);
    const unsigned short* kg[2];
    const unsigned short* vg[2];
    #pragma unroll
    for (int grp = 0; grp < 2; grp++) {
        const int r = wid * 16 + grp * 8 + rl;
        kg[grp] = kh + (size_t)r * HD + cc * 8;      // advance by 64*HD per tile
        vg[grp] = vh + (size_t)r * TT + cc * 8;      // advance by 64 per tile
    }
    const int ldsK0 = wid * 16 * 64, ldsK1 = (wid * 16 + 8) * 64;

    // prologue: stage tile 0 into buffer 0
    async16(kg[0], &Ks[0][ldsK0]);  async16(kg[1], &Ks[0][ldsK1]);
    async16(vg[0], &Vs[0][ldsK0]);  async16(vg[1], &Vs[0][ldsK1]);

    for (int t = 0; t < ntiles; t++) {
        __syncthreads();
        const int cur = t & 1;
        if (t + 1 < ntiles) {
            const int adv = (t + 1) * 64;
            async16(kg[0] + (size_t)adv * HD, &Ks[cur ^ 1][ldsK0]);
            async16(kg[1] + (size_t)adv * HD, &Ks[cur ^ 1][ldsK1]);
            async16(vg[0] + adv,              &Vs[cur ^ 1][ldsK0]);
            async16(vg[1] + adv,              &Vs[cur ^ 1][ldsK1]);
        }
        const int tk0 = t * 64;
        if (tk0 > q0w + 31) continue;                // wave fully masked (uniform)

        const unsigned short* Kc = Ks[cur];
        const unsigned short* Vc = Vs[cur];
        const int p0 = quad ^ (l16 & 7);
        const int p1 = (4 + quad) ^ (l16 & 7);
        s16x8 kf[4][2], vf[4][2];
        #pragma unroll
        for (int nj = 0; nj < 4; nj++) {
            kf[nj][0] = *(const s16x8*)&Kc[(nj * 16 + l16) * 64 + p0 * 8];
            kf[nj][1] = *(const s16x8*)&Kc[(nj * 16 + l16) * 64 + p1 * 8];
        }
        #pragma unroll
        for (int ni = 0; ni < 4; ni++) {
            vf[ni][0] = *(const s16x8*)&Vc[(ni * 16 + l16) * 64 + p0 * 8];
            vf[ni][1] = *(const s16x8*)&Vc[(ni * 16 + l16) * 64 + p1 * 8];
        }

        // phase 1: S^T = K*Q^T, exp2, packed b64 P-writes
        #pragma unroll
        for (int mf = 0; mf < 2; mf++) {
            const int f0 = q0w + mf * 16;
            if (tk0 > f0 + 15) continue;
            unsigned short* pm = ps + mf * (16 * PST);
            const int qg = f0 + l16;                 // this lane's q row
            f32x4 st[4];
            #pragma unroll
            for (int nj = 0; nj < 4; nj++) {
                f32x4 z = {};
                z = __builtin_amdgcn_mfma_f32_16x16x32_bf16(kf[nj][0], aq[mf][0], z, 0, 0, 0);
                z = __builtin_amdgcn_mfma_f32_16x16x32_bf16(kf[nj][1], aq[mf][1], z, 0, 0, 0);
                st[nj] = z;
            }
            const bool diag = (tk0 + 64 > f0);
            #pragma unroll
            for (int nj = 0; nj < 4; nj++) {
                const int keyb = tk0 + nj * 16 + quad * 4;
                float pv[4];
                #pragma unroll
                for (int r = 0; r < 4; r++) {
                    float p = exp2f(st[nj][r]);
                    if (diag && (keyb + r > qg)) p = 0.f;
                    pv[r] = p;
                }
                const unsigned int pk0 = (__float_as_uint(pv[0]) >> 16) |
                                         (__float_as_uint(pv[1]) & 0xffff0000u);
                const unsigned int pk1 = (__float_as_uint(pv[2]) >> 16) |
                                         (__float_as_uint(pv[3]) & 0xffff0000u);
                *(uint2*)&pm[l16 * PST + nj * 16 + quad * 4] = make_uint2(pk0, pk1);
            }
        }
        __asm volatile("s_waitcnt lgkmcnt(0)" ::: "memory");   // wave-private P visible
        // phase 2: PV + row-sum MFMA
        #pragma unroll
        for (int mf = 0; mf < 2; mf++) {
            const int f0 = q0w + mf * 16;
            if (tk0 > f0 + 15) continue;
            const unsigned short* pm = ps + mf * (16 * PST);
            const s16x8 ap0 = *(const s16x8*)&pm[l16 * PST + quad * 8];
            const s16x8 ap1 = *(const s16x8*)&pm[l16 * PST + 32 + quad * 8];
            lacc[mf] = __builtin_amdgcn_mfma_f32_16x16x32_bf16(ap0, onesf, lacc[mf], 0, 0, 0);
            lacc[mf] = __builtin_amdgcn_mfma_f32_16x16x32_bf16(ap1, onesf, lacc[mf], 0, 0, 0);
            #pragma unroll
            for (int ni = 0; ni < 4; ni++) {
                yacc[mf][ni] = __builtin_amdgcn_mfma_f32_16x16x32_bf16(ap0, vf[ni][0], yacc[mf][ni], 0, 0, 0);
                yacc[mf][ni] = __builtin_amdgcn_mfma_f32_16x16x32_bf16(ap1, vf[ni][1], yacc[mf][ni], 0, 0, 0);
            }
        }
    }

    // epilogue: lacc[mf][r] is the denominator for q = f0 + quad*4 + r — the exact
    // same (quad,r) indexing as yacc. No cross-lane reduction needed.
    const int bbi = bh >> 4, hh = bh & 15;
    #pragma unroll
    for (int mf = 0; mf < 2; mf++) {
        float linv[4];
        #pragma unroll
        for (int r = 0; r < 4; r++)
            linv[r] = 1.0f / lacc[mf][r];
        #pragma unroll
        for (int ni = 0; ni < 4; ni++)
            #pragma unroll
            for (int r = 0; r < 4; r++) {
                const int trow = q0w + mf * 16 + quad * 4 + r;
                yb[((size_t)bbi * TT + trow) * NE + hh * HD + ni * 16 + l16] =
                    f2bf(yacc[mf][ni][r] * linv[r]);
            }
    }
}

extern "C" void kernel_launch(void* const* d_in, const int* in_sizes, int n_in,
                              void* d_out, int out_size, void* d_ws, size_t ws_size,
                              hipStream_t stream) {
    const float* x      = (const float*)d_in[0];
    const float* ln_w   = (const float*)d_in[1];
    const float* ln_b   = (const float*)d_in[2];
    const float* W_attn = (const float*)d_in[3];
    const float* b_attn = (const float*)d_in[4];
    const float* W_proj = (const float*)d_in[5];
    const float* b_proj = (const float*)d_in[6];
    float* out = (float*)d_out;

    char* ws = (char*)d_ws;
    unsigned short* h    = (unsigned short*)ws;  ws += (size_t)MM * C_IN * 2;
    unsigned short* Wat  = (unsigned short*)ws;  ws += (size_t)N_QKV * C_IN * 2;
    unsigned short* Wpt  = (unsigned short*)ws;  ws += (size_t)NE * NE * 2;
    unsigned short* qbuf = (unsigned short*)ws;  ws += (size_t)MM * NE * 2;
    unsigned short* kbuf = (unsigned short*)ws;  ws += (size_t)MM * NE * 2;
    unsigned short* vtbf = (unsigned short*)ws;  ws += (size_t)MM * NE * 2;
    unsigned short* ybuf = (unsigned short*)ws;  ws += (size_t)MM * NE * 2;

    ln_kernel<<<MM, 256, 0, stream>>>(x, ln_w, ln_b, h);
    transpose_cast<<<dim3(N_QKV / 32, C_IN / 32), 256, 0, stream>>>(W_attn, Wat, C_IN, N_QKV);
    transpose_cast<<<dim3(NE / 32, NE / 32), 256, 0, stream>>>(W_proj, Wpt, NE, NE);
    gemm_bt<0><<<dim3(N_QKV / 128, MM / 128), 256, 0, stream>>>(h, Wat, b_attn, qbuf, kbuf, vtbf,
                                                                MM, N_QKV, C_IN);
    attn_kernel<<<64 * 16, 256, 0, stream>>>(qbuf, kbuf, vtbf, ybuf);
    gemm_bt<1><<<dim3(NE / 128, MM / 128), 256, 0, stream>>>(ybuf, Wpt, b_proj, out, nullptr, nullptr,
                                                             MM, NE, NE);
}

// Round 8
// 309.367 us; speedup vs baseline: 1.0584x; 1.0584x over previous
//
#include <hip/hip_runtime.h>
#include <hip/hip_bf16.h>

// ---- constants for this problem ----
#define BB 4
#define TT 2048
#define C_IN 1152
#define NE 1024
#define NH 16
#define HD 64
#define MM (BB*TT)          // 8192
#define N_QKV (3*NE)        // 3072

typedef __attribute__((ext_vector_type(8))) short s16x8;
typedef __attribute__((ext_vector_type(4))) float f32x4;

static __device__ __forceinline__ unsigned short f2bf(float x) {
    unsigned int u = __float_as_uint(x);
    unsigned int r = (u + 0x7fffu + ((u >> 16) & 1u)) >> 16;
    return (unsigned short)r;
}

// async global->LDS, 16 B per lane. LDS dest = wave-uniform base + lane*16.
static __device__ __forceinline__ void async16(const void* g, void* l) {
    __builtin_amdgcn_global_load_lds((const __attribute__((address_space(1))) void*)g,
                                     (__attribute__((address_space(3))) void*)l, 16, 0, 0);
}

// ---------------- LayerNorm: x fp32 [M][C_IN] -> h bf16 [M][C_IN] ----------------
__global__ __launch_bounds__(256) void ln_kernel(const float* __restrict__ x,
                                                 const float* __restrict__ w,
                                                 const float* __restrict__ b,
                                                 unsigned short* __restrict__ h) {
    const int row = blockIdx.x;
    const float* xr = x + (size_t)row * C_IN;
    float s = 0.f, sq = 0.f;
    for (int i = threadIdx.x; i < C_IN; i += 256) {
        float v = xr[i];
        s += v; sq += v * v;
    }
    for (int off = 1; off < 64; off <<= 1) {
        s  += __shfl_xor(s, off, 64);
        sq += __shfl_xor(sq, off, 64);
    }
    __shared__ float red[2][4];
    const int wid = threadIdx.x >> 6, lane = threadIdx.x & 63;
    if (lane == 0) { red[0][wid] = s; red[1][wid] = sq; }
    __syncthreads();
    s  = red[0][0] + red[0][1] + red[0][2] + red[0][3];
    sq = red[1][0] + red[1][1] + red[1][2] + red[1][3];
    const float mu  = s * (1.f / C_IN);
    const float var = sq * (1.f / C_IN) - mu * mu;
    const float rs  = rsqrtf(var + 1e-5f);
    unsigned short* hr = h + (size_t)row * C_IN;
    for (int i = threadIdx.x; i < C_IN; i += 256) {
        float v = (xr[i] - mu) * rs * w[i] + b[i];
        hr[i] = f2bf(v);
    }
}

// ------------- transpose+cast: in fp32 [K][N] -> out bf16 [N][K] -------------
__global__ __launch_bounds__(256) void transpose_cast(const float* __restrict__ in,
                                                      unsigned short* __restrict__ out,
                                                      int K, int N) {
    __shared__ float tile[32][33];
    const int n0 = blockIdx.x * 32, k0 = blockIdx.y * 32;
    const int tx = threadIdx.x & 31, ty = threadIdx.x >> 5;   // 32 x 8
    for (int i = ty; i < 32; i += 8)
        tile[i][tx] = in[(size_t)(k0 + i) * N + n0 + tx];
    __syncthreads();
    for (int i = ty; i < 32; i += 8)
        out[(size_t)(n0 + i) * K + k0 + tx] = f2bf(tile[tx][i]);
}

#define ATT_SC 0.18033688011112042f   /* (1/8) * log2(e) */

// ------------- GEMM: A bf16 [M][K] x Bt bf16 [N][K] + bias -> epilogue -------------
// Double-buffered global_load_lds staging, one barrier per k-tile.
// MODE 0: QKV with LDS-routed coalesced epilogue; t = batch-local (mg & 2047).
//         q is PRE-SCALED by ATT_SC.
// MODE 1: plain fp32 out [M][N] direct stores.
#define EP_STRIDE 136   /* ushort; 272 B rows keep 16 B alignment for b128 */
template <int MODE>
__global__ __launch_bounds__(256) void gemm_bt(const unsigned short* __restrict__ A,
                                               const unsigned short* __restrict__ Bt,
                                               const float* __restrict__ bias,
                                               void* __restrict__ outp,
                                               unsigned short* __restrict__ kb,
                                               unsigned short* __restrict__ vt,
                                               int M, int N, int K) {
    __shared__ unsigned short smem[16384];          // 32 KB
    unsigned short* As = smem;                      // [2][128*32]
    unsigned short* Bs = smem + 8192;
    const int tid = threadIdx.x;
    const int wid = tid >> 6, lane = tid & 63;
    const int wm = wid >> 1, wn = wid & 1;
    const int quad = lane >> 4, l16 = lane & 15;
    const int m0 = blockIdx.y * 128, n0 = blockIdx.x * 128;

    const int srow = wid * 32 + (lane >> 2);     // + {0,16}
    const int scol = (lane & 3) * 8;
    const unsigned short* gA = A  + (size_t)(m0 + srow) * K + scol;
    const unsigned short* gB = Bt + (size_t)(n0 + srow) * K + scol;
    const int lofs = (wid * 32) * 32;

    f32x4 acc[4][4] = {};

    async16(gA,          &As[lofs]);
    async16(gA + 16 * K, &As[lofs + 16 * 32]);
    async16(gB,          &Bs[lofs]);
    async16(gB + 16 * K, &Bs[lofs + 16 * 32]);

    const int nk = K >> 5;
    for (int kt = 0; kt < nk; kt++) {
        __syncthreads();
        const int cur = kt & 1;
        if (kt + 1 < nk) {
            const int kk = (kt + 1) << 5;
            const int nxt = (cur ^ 1) * 4096;
            async16(gA + kk,          &As[nxt + lofs]);
            async16(gA + kk + 16 * K, &As[nxt + lofs + 16 * 32]);
            async16(gB + kk,          &Bs[nxt + lofs]);
            async16(gB + kk + 16 * K, &Bs[nxt + lofs + 16 * 32]);
        }
        const int cb = cur * 4096;
        s16x8 af[4], bfb[4];
        for (int mi = 0; mi < 4; mi++)
            af[mi] = *(const s16x8*)&As[cb + (wm * 64 + mi * 16 + l16) * 32 + quad * 8];
        for (int ni = 0; ni < 4; ni++)
            bfb[ni] = *(const s16x8*)&Bs[cb + (wn * 64 + ni * 16 + l16) * 32 + quad * 8];
        for (int mi = 0; mi < 4; mi++)
            for (int ni = 0; ni < 4; ni++)
                acc[mi][ni] = __builtin_amdgcn_mfma_f32_16x16x32_bf16(af[mi], bfb[ni], acc[mi][ni], 0, 0, 0);
    }

    // bias into registers (+ ATT_SC pre-scale for the q third)
    const int which0 = n0 >> 10;
    const float sc = (MODE == 0 && which0 == 0) ? ATT_SC : 1.0f;
    for (int ni = 0; ni < 4; ni++) {
        const float bv = bias[n0 + wn * 64 + ni * 16 + l16];
        for (int mi = 0; mi < 4; mi++)
            for (int r = 0; r < 4; r++)
                acc[mi][ni][r] = (acc[mi][ni][r] + bv) * sc;
    }

    if (MODE == 1) {
        for (int mi = 0; mi < 4; mi++) {
            const int mbase = m0 + wm * 64 + mi * 16 + quad * 4;
            for (int ni = 0; ni < 4; ni++) {
                const int n_g = n0 + wn * 64 + ni * 16 + l16;
                for (int r = 0; r < 4; r++)
                    ((float*)outp)[(size_t)(mbase + r) * N + n_g] = acc[mi][ni][r];
            }
        }
        return;
    }

    // ---- MODE 0: LDS-routed coalesced epilogue ----
    const int which = n0 >> 10;                    // 0=q 1=k 2=v (uniform)
    const int bb = m0 >> 11;
    const int mloc = m0 & 2047;                    // batch-local time base
    unsigned short* T = smem;                      // [64][EP_STRIDE]

    if (which < 2) {
        // row layout [m_local 64][n_local 128]; two m-half passes
        unsigned short* qk = (which == 0) ? (unsigned short*)outp : kb;
        for (int pass = 0; pass < 2; pass++) {
            __syncthreads();
            if (wm == pass) {
                for (int mi = 0; mi < 4; mi++)
                    for (int ni = 0; ni < 4; ni++) {
                        const int nl = wn * 64 + ni * 16 + l16;
                        for (int r = 0; r < 4; r++)
                            T[(mi * 16 + quad * 4 + r) * EP_STRIDE + nl] = f2bf(acc[mi][ni][r]);
                    }
            }
            __syncthreads();
            const int ml = tid >> 2, c = tid & 3;
            const int t  = mloc + pass * 64 + ml;
            const int nl0 = c * 32;
            const int hh = ((n0 & 1023) >> 6) + (nl0 >> 6);
            const int d0 = nl0 & 63;
            unsigned short* dst = qk + ((size_t)(bb * 16 + hh) * TT + t) * HD + d0;
            const unsigned short* src = &T[ml * EP_STRIDE + nl0];
            for (int u = 0; u < 4; u++)
                *(s16x8*)(dst + u * 8) = *(const s16x8*)(src + u * 8);
        }
    } else {
        // transposed layout [n_local 64][m_local 128]; two n-half passes
        for (int pass = 0; pass < 2; pass++) {
            __syncthreads();
            if (wn == pass) {
                for (int mi = 0; mi < 4; mi++)
                    for (int ni = 0; ni < 4; ni++) {
                        const int nlh = ni * 16 + l16;
                        const int mlb = wm * 64 + mi * 16 + quad * 4;
                        for (int r = 0; r < 4; r += 2) {
                            const unsigned int pk = (unsigned int)f2bf(acc[mi][ni][r]) |
                                                    ((unsigned int)f2bf(acc[mi][ni][r + 1]) << 16);
                            *(unsigned int*)&T[nlh * EP_STRIDE + mlb + r] = pk;
                        }
                    }
            }
            __syncthreads();
            const int nlh = tid >> 2, c = tid & 3;
            const int hh = (n0 - 2048 + pass * 64) >> 6;
            unsigned short* dst = vt + ((size_t)(bb * 16 + hh) * HD + nlh) * TT + mloc + c * 32;
            const unsigned short* src = &T[nlh * EP_STRIDE + c * 32];
            for (int u = 0; u < 4; u++)
                *(s16x8*)(dst + u * 8) = *(const s16x8*)(src + u * 8);
        }
    }
}

// ------------- flash attention: S^T trick + ones-MFMA row sums -------------
// q (pre-scaled by ATT_SC), k [BH][T][64] bf16, vt [BH][64][T] bf16 -> y bf16 [B][T][NE]
// k-loop unrolled x2 with COMPILE-TIME buffer index: all LDS fragment/P addresses
// become loop-invariant lane constants (LICM + ds offset immediates).
#define PST 72                         /* shorts; 144 B rows, 16B-aligned */

__global__ __launch_bounds__(256) void attn_kernel(const unsigned short* __restrict__ qb,
                                                   const unsigned short* __restrict__ kb,
                                                   const unsigned short* __restrict__ vt,
                                                   unsigned short* __restrict__ yb) {
    __shared__ unsigned short Ks[2][64 * 64];
    __shared__ unsigned short Vs[2][64 * 64];
    __shared__ unsigned short Ps[4][2 * 16 * PST];   // per-wave, per-mf [16 q][PST]
    const int tid = threadIdx.x, wid = tid >> 6, lane = tid & 63;
    const int quad = lane >> 4, l16 = lane & 15;
    const int bh = blockIdx.x & 63;
    const int qblk = 15 - (blockIdx.x >> 6);         // longest-first (LPT packing)

    const unsigned short* qh = qb + (size_t)bh * TT * HD;
    const unsigned short* kh = kb + (size_t)bh * TT * HD;
    const unsigned short* vh = vt + (size_t)bh * HD * TT;
    unsigned short* ps = Ps[wid];

    const int q0w = qblk * 128 + wid * 32;           // this wave's 32 q-rows
    s16x8 aq[2][2];
    #pragma unroll
    for (int mf = 0; mf < 2; mf++) {
        aq[mf][0] = *(const s16x8*)&qh[(size_t)(q0w + mf * 16 + l16) * HD + quad * 8];
        aq[mf][1] = *(const s16x8*)&qh[(size_t)(q0w + mf * 16 + l16) * HD + 32 + quad * 8];
    }
    // ones B-frag (bf16 1.0 = 0x3F80)
    s16x8 onesf;
    #pragma unroll
    for (int i = 0; i < 8; i++) onesf[i] = (short)0x3F80;

    f32x4 yacc[2][4] = {};
    f32x4 lacc[2] = {};                              // row-sum accumulators
    const int ntiles = 2 * qblk + 2;                 // always even

    // staging: row r = wid*16 + {0,8} + rl, chunk cc XOR-swizzled; pointers bumped
    const int rl = lane >> 3;
    const int cc = (lane & 7) ^ (rl & 7);
    const unsigned short* kp0 = kh + (size_t)(wid * 16 + rl) * HD + cc * 8;
    const unsigned short* kp1 = kh + (size_t)(wid * 16 + 8 + rl) * HD + cc * 8;
    const unsigned short* vp0 = vh + (size_t)(wid * 16 + rl) * TT + cc * 8;
    const unsigned short* vp1 = vh + (size_t)(wid * 16 + 8 + rl) * TT + cc * 8;
    const int ldsK0 = wid * 16 * 64, ldsK1 = (wid * 16 + 8) * 64;

    // prologue: stage tile 0 into buffer 0; bump to tile 1
    async16(kp0, &Ks[0][ldsK0]);  async16(kp1, &Ks[0][ldsK1]);
    async16(vp0, &Vs[0][ldsK0]);  async16(vp1, &Vs[0][ldsK1]);
    kp0 += 64 * HD; kp1 += 64 * HD; vp0 += 64; vp1 += 64;

    const int p0s = quad ^ (l16 & 7);
    const int p1s = (4 + quad) ^ (l16 & 7);

#define ATT_STEP(CUR, TT_)                                                              \
    {                                                                                   \
        __syncthreads();                                                                \
        if ((TT_) + 1 < ntiles) {                                                       \
            async16(kp0, &Ks[(CUR) ^ 1][ldsK0]);  async16(kp1, &Ks[(CUR) ^ 1][ldsK1]);  \
            async16(vp0, &Vs[(CUR) ^ 1][ldsK0]);  async16(vp1, &Vs[(CUR) ^ 1][ldsK1]);  \
            kp0 += 64 * HD; kp1 += 64 * HD; vp0 += 64; vp1 += 64;                       \
        }                                                                               \
        const int tk0 = (TT_) * 64;                                                     \
        if (tk0 <= q0w + 31) {                                                          \
            const unsigned short* Kc = Ks[CUR];                                         \
            const unsigned short* Vc = Vs[CUR];                                         \
            s16x8 kf[4][2], vf[4][2];                                                   \
            _Pragma("unroll")                                                           \
            for (int nj = 0; nj < 4; nj++) {                                            \
                kf[nj][0] = *(const s16x8*)&Kc[(nj * 16 + l16) * 64 + p0s * 8];         \
                kf[nj][1] = *(const s16x8*)&Kc[(nj * 16 + l16) * 64 + p1s * 8];         \
            }                                                                           \
            _Pragma("unroll")                                                           \
            for (int ni = 0; ni < 4; ni++) {                                            \
                vf[ni][0] = *(const s16x8*)&Vc[(ni * 16 + l16) * 64 + p0s * 8];         \
                vf[ni][1] = *(const s16x8*)&Vc[(ni * 16 + l16) * 64 + p1s * 8];         \
            }                                                                           \
            _Pragma("unroll")                                                           \
            for (int mf = 0; mf < 2; mf++) {                                            \
                const int f0 = q0w + mf * 16;                                           \
                if (tk0 > f0 + 15) continue;                                            \
                unsigned short* pm = ps + mf * (16 * PST);                              \
                const int qg = f0 + l16;                                                \
                f32x4 st[4];                                                            \
                _Pragma("unroll")                                                       \
                for (int nj = 0; nj < 4; nj++) {                                        \
                    f32x4 z = {};                                                       \
                    z = __builtin_amdgcn_mfma_f32_16x16x32_bf16(kf[nj][0], aq[mf][0], z, 0, 0, 0); \
                    z = __builtin_amdgcn_mfma_f32_16x16x32_bf16(kf[nj][1], aq[mf][1], z, 0, 0, 0); \
                    st[nj] = z;                                                         \
                }                                                                       \
                const bool diag = (tk0 + 64 > f0);                                      \
                _Pragma("unroll")                                                       \
                for (int nj = 0; nj < 4; nj++) {                                        \
                    const int keyb = tk0 + nj * 16 + quad * 4;                          \
                    float pv[4];                                                        \
                    _Pragma("unroll")                                                   \
                    for (int r = 0; r < 4; r++) {                                       \
                        float p = exp2f(st[nj][r]);                                     \
                        if (diag && (keyb + r > qg)) p = 0.f;                           \
                        pv[r] = p;                                                      \
                    }                                                                   \
                    const unsigned int pk0 = __builtin_amdgcn_perm(                     \
                        __float_as_uint(pv[1]), __float_as_uint(pv[0]), 0x07060302u);   \
                    const unsigned int pk1 = __builtin_amdgcn_perm(                     \
                        __float_as_uint(pv[3]), __float_as_uint(pv[2]), 0x07060302u);   \
                    *(uint2*)&pm[l16 * PST + nj * 16 + quad * 4] = make_uint2(pk0, pk1);\
                }                                                                       \
                __asm volatile("s_waitcnt lgkmcnt(0)" ::: "memory");                    \
                const s16x8 ap0 = *(const s16x8*)&pm[l16 * PST + quad * 8];             \
                const s16x8 ap1 = *(const s16x8*)&pm[l16 * PST + 32 + quad * 8];        \
                lacc[mf] = __builtin_amdgcn_mfma_f32_16x16x32_bf16(ap0, onesf, lacc[mf], 0, 0, 0); \
                lacc[mf] = __builtin_amdgcn_mfma_f32_16x16x32_bf16(ap1, onesf, lacc[mf], 0, 0, 0); \
                _Pragma("unroll")                                                       \
                for (int ni = 0; ni < 4; ni++) {                                        \
                    yacc[mf][ni] = __builtin_amdgcn_mfma_f32_16x16x32_bf16(ap0, vf[ni][0], yacc[mf][ni], 0, 0, 0); \
                    yacc[mf][ni] = __builtin_amdgcn_mfma_f32_16x16x32_bf16(ap1, vf[ni][1], yacc[mf][ni], 0, 0, 0); \
                }                                                                       \
            }                                                                           \
        }                                                                               \
    }

    for (int t = 0; t < ntiles; t += 2) {
        ATT_STEP(0, t);
        ATT_STEP(1, t + 1);
    }
#undef ATT_STEP

    // epilogue: lacc[mf][r] is the denominator for q = f0 + quad*4 + r — the exact
    // same (quad,r) indexing as yacc. No cross-lane reduction needed.
    const int bbi = bh >> 4, hh = bh & 15;
    #pragma unroll
    for (int mf = 0; mf < 2; mf++) {
        float linv[4];
        #pragma unroll
        for (int r = 0; r < 4; r++)
            linv[r] = 1.0f / lacc[mf][r];
        #pragma unroll
        for (int ni = 0; ni < 4; ni++)
            #pragma unroll
            for (int r = 0; r < 4; r++) {
                const int trow = q0w + mf * 16 + quad * 4 + r;
                yb[((size_t)bbi * TT + trow) * NE + hh * HD + ni * 16 + l16] =
                    f2bf(yacc[mf][ni][r] * linv[r]);
            }
    }
}

extern "C" void kernel_launch(void* const* d_in, const int* in_sizes, int n_in,
                              void* d_out, int out_size, void* d_ws, size_t ws_size,
                              hipStream_t stream) {
    const float* x      = (const float*)d_in[0];
    const float* ln_w   = (const float*)d_in[1];
    const float* ln_b   = (const float*)d_in[2];
    const float* W_attn = (const float*)d_in[3];
    const float* b_attn = (const float*)d_in[4];
    const float* W_proj = (const float*)d_in[5];
    const float* b_proj = (const float*)d_in[6];
    float* out = (float*)d_out;

    char* ws = (char*)d_ws;
    unsigned short* h    = (unsigned short*)ws;  ws += (size_t)MM * C_IN * 2;
    unsigned short* Wat  = (unsigned short*)ws;  ws += (size_t)N_QKV * C_IN * 2;
    unsigned short* Wpt  = (unsigned short*)ws;  ws += (size_t)NE * NE * 2;
    unsigned short* qbuf = (unsigned short*)ws;  ws += (size_t)MM * NE * 2;
    unsigned short* kbuf = (unsigned short*)ws;  ws += (size_t)MM * NE * 2;
    unsigned short* vtbf = (unsigned short*)ws;  ws += (size_t)MM * NE * 2;
    unsigned short* ybuf = (unsigned short*)ws;  ws += (size_t)MM * NE * 2;

    ln_kernel<<<MM, 256, 0, stream>>>(x, ln_w, ln_b, h);
    transpose_cast<<<dim3(N_QKV / 32, C_IN / 32), 256, 0, stream>>>(W_attn, Wat, C_IN, N_QKV);
    transpose_cast<<<dim3(NE / 32, NE / 32), 256, 0, stream>>>(W_proj, Wpt, NE, NE);
    gemm_bt<0><<<dim3(N_QKV / 128, MM / 128), 256, 0, stream>>>(h, Wat, b_attn, qbuf, kbuf, vtbf,
                                                                MM, N_QKV, C_IN);
    attn_kernel<<<64 * 16, 256, 0, stream>>>(qbuf, kbuf, vtbf, ybuf);
    gemm_bt<1><<<dim3(NE / 128, MM / 128), 256, 0, stream>>>(ybuf, Wpt, b_proj, out, nullptr, nullptr,
                                                             MM, NE, NE);
}